// Round 1
// baseline (102.615 us; speedup 1.0000x reference)
//
#include <hip/hip_runtime.h>

// Tree-structured parent-child attention.
// Shapes (from reference setup): B=8, N=2048, H=16, D=64. All fp32.
// Parent row (b,n,h) attends to {K_p[b,n,h], K_c[b,2n,h], K_c[b,2n+1,h]}
// with a 3-way softmax (eps=1e-9 in denominator), output fp32 [B,N,H,D].
//
// Memory-bound: ~512 MiB total traffic. Layout: one 256-thread block per
// (b,n): 16 heads x 16 lanes, each lane owns a float4 (16B) of the D=64 row.

#define D_DIM 64

__global__ __launch_bounds__(256) void tree_attn_kernel(
    const float* __restrict__ Qp,
    const float* __restrict__ Kp,
    const float* __restrict__ Vp,
    const float* __restrict__ Kc,
    const float* __restrict__ Vc,
    float* __restrict__ out,
    int N, int H)
{
    const int bn   = blockIdx.x;          // b*N + n
    const int b    = bn / N;
    const int n    = bn - b * N;
    const int h    = threadIdx.x >> 4;    // 0..15 (H=16)
    const int lane = threadIdx.x & 15;    // 0..15, each owns 4 floats

    // Parent row base: ((b*N + n)*H + h) * D
    const size_t rowP  = ((size_t)bn * H + h) * D_DIM;
    // Child rows: ((b*2N + 2n)*H + h) * D and next child (+H*D)
    const size_t rowC0 = (((size_t)b * 2 * N + 2 * n) * H + h) * D_DIM;
    const size_t rowC1 = rowC0 + (size_t)H * D_DIM;

    const int off = lane * 4;

    const float4 q   = *(const float4*)(Qp + rowP  + off);
    const float4 kp  = *(const float4*)(Kp + rowP  + off);
    const float4 kc0 = *(const float4*)(Kc + rowC0 + off);
    const float4 kc1 = *(const float4*)(Kc + rowC1 + off);

    float s0 = q.x * kp.x  + q.y * kp.y  + q.z * kp.z  + q.w * kp.w;
    float s1 = q.x * kc0.x + q.y * kc0.y + q.z * kc0.z + q.w * kc0.w;
    float s2 = q.x * kc1.x + q.y * kc1.y + q.z * kc1.z + q.w * kc1.w;

    // Reduce across the 16-lane group (xor masks 1..8 stay in-group on wave64).
    #pragma unroll
    for (int m = 8; m >= 1; m >>= 1) {
        s0 += __shfl_xor(s0, m);
        s1 += __shfl_xor(s1, m);
        s2 += __shfl_xor(s2, m);
    }

    const float scale = 0.125f;  // 1/sqrt(64)
    s0 *= scale; s1 *= scale; s2 *= scale;

    const float mx = fmaxf(s0, fmaxf(s1, s2));
    const float e0 = expf(s0 - mx);
    const float e1 = expf(s1 - mx);
    const float e2 = expf(s2 - mx);
    const float inv = 1.0f / (e0 + e1 + e2 + 1e-9f);
    const float w0 = e0 * inv, w1 = e1 * inv, w2 = e2 * inv;

    const float4 vp  = *(const float4*)(Vp + rowP  + off);
    const float4 vc0 = *(const float4*)(Vc + rowC0 + off);
    const float4 vc1 = *(const float4*)(Vc + rowC1 + off);

    float4 o;
    o.x = w0 * vp.x + w1 * vc0.x + w2 * vc1.x;
    o.y = w0 * vp.y + w1 * vc0.y + w2 * vc1.y;
    o.z = w0 * vp.z + w1 * vc0.z + w2 * vc1.z;
    o.w = w0 * vp.w + w1 * vc0.w + w2 * vc1.w;

    *(float4*)(out + rowP + off) = o;
}

extern "C" void kernel_launch(void* const* d_in, const int* in_sizes, int n_in,
                              void* d_out, int out_size, void* d_ws, size_t ws_size,
                              hipStream_t stream) {
    (void)n_in; (void)d_ws; (void)ws_size; (void)out_size;

    const float* Qp = (const float*)d_in[0];
    const float* Kp = (const float*)d_in[1];
    const float* Vp = (const float*)d_in[2];
    const float* Kc = (const float*)d_in[3];
    const float* Vc = (const float*)d_in[4];
    float* out = (float*)d_out;

    // Reference shapes: B=8, N=2048, H=16, D=64.
    const int B = 8, N = 2048, H = 16;
    (void)in_sizes;

    dim3 grid(B * N);   // 16384 blocks, one per (b,n)
    dim3 block(256);    // 16 heads x 16 lanes
    tree_attn_kernel<<<grid, block, 0, stream>>>(Qp, Kp, Vp, Kc, Vc, out, N, H);
}